// Round 8
// baseline (59.487 us; speedup 1.0000x reference)
//
#include <hip/hip_runtime.h>
#include <hip/hip_cooperative_groups.h>
#include <math.h>

namespace cg = cooperative_groups;

// Chamfer loss, B=8, N=M=4096, D=3, fp32. Single cooperative kernel.
// 256 blocks = (dir, batch, 256-query chunk), T=1024 (16 waves, 4/SIMD),
// 1 block/CU (81 KB LDS) -> co-residency guaranteed for grid.sync().
// Full 4096-pt target cloud staged in LDS as (t0,t1,t2,|t|^2) [64 KB].
// Thread (qrow=tid&31, slice=tid>>5): 8 queries, scans 128-target slice.
// d' = |t|^2 - 2 q.t ; v_min3_f32 folds the pair-min (3.5 VALU ops/pair).
// |q|^2 + clamp deferred past the cross-slice min.
// After grid.sync(), block 0 reduces the 256 weighted partials -> out.

constexpr int BATCH = 8;
constexpr int NP    = 4096;   // points per cloud
constexpr int T     = 1024;   // threads per block (16 waves, 4/SIMD)
constexpr int QPB   = 256;    // queries per block
constexpr int KPT   = 8;      // queries per thread
constexpr int S     = 32;     // target slices (threads per query column)
constexpr int TPS   = 128;    // targets per slice
constexpr int NBLK  = 256;

__global__ __launch_bounds__(T, 4) void chamfer_all(
    const float* __restrict__ x, const float* __restrict__ y,
    const float* __restrict__ w, float* __restrict__ ps,
    float* __restrict__ out)
{
    const int bid = blockIdx.x;          // dir(1b) | b(3b) | qc(4b)
    const int dir = bid >> 7;
    const int b   = (bid >> 4) & 7;
    const int qc  = bid & 15;

    const float* q = dir ? y : x;
    const float* t = dir ? x : y;

    __shared__ float4 ty[NP];            // 64 KB target stage
    __shared__ float  pmin[S / 2][QPB];  // 16 KB cross-slice-pair mins
    __shared__ float  qn[QPB];           // |q|^2 per query
    __shared__ float  rsum[T / 64];

    const int tid = threadIdx.x;

    // stage all 4096 targets of batch b (lane l -> ty[l]: conflict-free b128)
    const float* tb = t + (size_t)b * NP * 3;
    for (int j = tid; j < NP; j += T) {
        float t0 = tb[3 * j + 0];
        float t1 = tb[3 * j + 1];
        float t2 = tb[3 * j + 2];
        ty[j] = make_float4(t0, t1, t2, fmaf(t0, t0, fmaf(t1, t1, t2 * t2)));
    }

    // this thread's 8 queries (24 consecutive floats, 16B-aligned)
    const int qrow  = tid & 31;
    const int slice = tid >> 5;          // [0,32); wave = slices {2w, 2w+1}
    const int n0 = b * NP + qc * QPB + qrow * KPT;
    const float4* qb = reinterpret_cast<const float4*>(q + (size_t)n0 * 3);
    float4 v0 = qb[0], v1 = qb[1], v2 = qb[2], v3 = qb[3], v4 = qb[4], v5 = qb[5];
    float px[KPT][3] = {
        {v0.x, v0.y, v0.z}, {v0.w, v1.x, v1.y},
        {v1.z, v1.w, v2.x}, {v2.y, v2.z, v2.w},
        {v3.x, v3.y, v3.z}, {v3.w, v4.x, v4.y},
        {v4.z, v4.w, v5.x}, {v5.y, v5.z, v5.w},
    };
    float xn[KPT][3], mn[KPT];
    #pragma unroll
    for (int k = 0; k < KPT; ++k) {
        float x2 = fmaf(px[k][0], px[k][0],
                   fmaf(px[k][1], px[k][1], px[k][2] * px[k][2]));
        if (slice == 0) qn[qrow * KPT + k] = x2;
        #pragma unroll
        for (int d = 0; d < 3; ++d) xn[k][d] = -2.0f * px[k][d];
        mn[k] = INFINITY;
    }

    __syncthreads();

    // min over this slice's targets of d' = |t|^2 - 2 q.t
    const int j0 = slice * TPS;
    #pragma unroll 4
    for (int j = j0; j < j0 + TPS; j += 2) {
        float4 ta = ty[j];               // 2 distinct addrs per wave (free)
        float4 tc = ty[j + 1];
        #pragma unroll
        for (int k = 0; k < KPT; ++k) {
            float da = fmaf(xn[k][0], ta.x,
                       fmaf(xn[k][1], ta.y, fmaf(xn[k][2], ta.z, ta.w)));
            float db = fmaf(xn[k][0], tc.x,
                       fmaf(xn[k][1], tc.y, fmaf(xn[k][2], tc.z, tc.w)));
            float m;
            asm("v_min3_f32 %0, %1, %2, %3"
                : "=v"(m) : "v"(mn[k]), "v"(da), "v"(db));
            mn[k] = m;                   // 3.5 VALU ops per pair
        }
    }

    // intra-wave combine of slice pairs (lanes l <-> l+32), then exchange
    #pragma unroll
    for (int k = 0; k < KPT; ++k)
        mn[k] = fminf(mn[k], __shfl_xor(mn[k], 32, 64));
    if ((slice & 1) == 0) {
        #pragma unroll
        for (int k = 0; k < KPT; ++k)
            pmin[slice >> 1][qrow * KPT + k] = mn[k];
    }
    __syncthreads();

    float val = 0.0f;
    if (tid < QPB) {                     // thread tid owns query tid
        float m = pmin[0][tid];
        #pragma unroll
        for (int s = 1; s < S / 2; ++s) m = fminf(m, pmin[s][tid]);
        val = fmaxf(qn[tid] + m, 0.0f);  // clamp after full min
    }

    // fixed-order block sum (other waves contribute 0)
    for (int off = 32; off; off >>= 1) val += __shfl_down(val, off, 64);
    if ((tid & 63) == 0) rsum[tid >> 6] = val;
    __syncthreads();
    if (tid == 0) {
        float s = 0.0f;
        #pragma unroll
        for (int i = 0; i < T / 64; ++i) s += rsum[i];
        ps[bid] = s * w[b] * (1.0f / ((float)NP * (float)BATCH));
    }

    // ---- grid-wide barrier, then block 0 reduces the 256 partials ----
    cg::this_grid().sync();

    if (bid == 0) {
        float v = (tid < NBLK) ? ps[tid] : 0.0f;
        for (int off = 32; off; off >>= 1) v += __shfl_down(v, off, 64);
        if ((tid & 63) == 0) rsum[tid >> 6] = v;   // waves 0-3 carry data
        __syncthreads();
        if (tid == 0)
            out[0] = (rsum[0] + rsum[1]) + (rsum[2] + rsum[3]);
    }
}

extern "C" void kernel_launch(void* const* d_in, const int* in_sizes, int n_in,
                              void* d_out, int out_size, void* d_ws, size_t ws_size,
                              hipStream_t stream) {
    const float* x = (const float*)d_in[0];   // (8, 4096, 3)
    const float* y = (const float*)d_in[1];   // (8, 4096, 3)
    const float* w = (const float*)d_in[2];   // (8,)
    float* out = (float*)d_out;
    float* ps  = (float*)d_ws;                // 256 floats

    void* args[] = { (void*)&x, (void*)&y, (void*)&w, (void*)&ps, (void*)&out };
    hipLaunchCooperativeKernel((const void*)chamfer_all, dim3(NBLK), dim3(T),
                               args, 0, stream);
}

// Round 9
// 27.554 us; speedup vs baseline: 2.1589x; 2.1589x over previous
//
#include <hip/hip_runtime.h>
#include <math.h>

// Chamfer loss, B=8, N=M=4096, D=3, fp32. Two kernels (r7 structure).
// k1: 256 blocks = (dir, batch, 256-query chunk), T=1024 (16 waves, 4/SIMD).
//     Full 4096-pt target cloud staged in LDS as (t0,t1,t2,|t|^2) [64 KB];
//     staging reads are 3x float4 per thread (48B contiguous).
//     Thread (qrow=tid&31, slice=tid>>5): 8 queries, scans 128-target slice.
//     Wave = 2 slices -> ds_read_b128 has 2 distinct addrs (free, m136).
//     d' = |t|^2 - 2 q.t ; v_min3_f32 folds the pair-min (3.5 ops/pair,
//     the exact VALU floor: 3 fma per 3D-dot+bias target).
//     |q|^2 + clamp deferred past the cross-slice min.
// k2: one wave sums the 256 weighted per-block partials (float4 loads).

constexpr int BATCH = 8;
constexpr int NP    = 4096;   // points per cloud
constexpr int T     = 1024;   // threads per block (16 waves, 4/SIMD)
constexpr int QPB   = 256;    // queries per block
constexpr int KPT   = 8;      // queries per thread
constexpr int S     = 32;     // target slices (threads per query column)
constexpr int TPS   = 128;    // targets per slice

__global__ __launch_bounds__(T, 4) void chamfer_main(
    const float* __restrict__ x, const float* __restrict__ y,
    const float* __restrict__ w, float* __restrict__ ps)
{
    const int bid = blockIdx.x;          // dir(1b) | b(3b) | qc(4b)
    const int dir = bid >> 7;
    const int b   = (bid >> 4) & 7;
    const int qc  = bid & 15;

    const float* q = dir ? y : x;
    const float* t = dir ? x : y;

    __shared__ float4 ty[NP];            // 64 KB target stage
    __shared__ float  pmin[S / 2][QPB];  // 16 KB cross-slice-pair mins
    __shared__ float  qn[QPB];           // |q|^2 per query
    __shared__ float  rsum[T / 64];

    const int tid = threadIdx.x;

    // stage all 4096 targets of batch b: 4 points = 3 float4 per thread
    {
        const float4* tf4 = reinterpret_cast<const float4*>(
            t + (size_t)b * NP * 3);
        float4 A = tf4[3 * tid + 0];
        float4 B = tf4[3 * tid + 1];
        float4 C = tf4[3 * tid + 2];
        const int j0 = tid * 4;
        ty[j0 + 0] = make_float4(A.x, A.y, A.z,
                     fmaf(A.x, A.x, fmaf(A.y, A.y, A.z * A.z)));
        ty[j0 + 1] = make_float4(A.w, B.x, B.y,
                     fmaf(A.w, A.w, fmaf(B.x, B.x, B.y * B.y)));
        ty[j0 + 2] = make_float4(B.z, B.w, C.x,
                     fmaf(B.z, B.z, fmaf(B.w, B.w, C.x * C.x)));
        ty[j0 + 3] = make_float4(C.y, C.z, C.w,
                     fmaf(C.y, C.y, fmaf(C.z, C.z, C.w * C.w)));
    }

    // this thread's 8 queries (24 consecutive floats, 16B-aligned)
    const int qrow  = tid & 31;
    const int slice = tid >> 5;          // [0,32); wave = slices {2w, 2w+1}
    const int n0 = b * NP + qc * QPB + qrow * KPT;
    const float4* qb = reinterpret_cast<const float4*>(q + (size_t)n0 * 3);
    float4 v0 = qb[0], v1 = qb[1], v2 = qb[2], v3 = qb[3], v4 = qb[4], v5 = qb[5];
    float px[KPT][3] = {
        {v0.x, v0.y, v0.z}, {v0.w, v1.x, v1.y},
        {v1.z, v1.w, v2.x}, {v2.y, v2.z, v2.w},
        {v3.x, v3.y, v3.z}, {v3.w, v4.x, v4.y},
        {v4.z, v4.w, v5.x}, {v5.y, v5.z, v5.w},
    };
    float xn[KPT][3], mn[KPT];
    #pragma unroll
    for (int k = 0; k < KPT; ++k) {
        float x2 = fmaf(px[k][0], px[k][0],
                   fmaf(px[k][1], px[k][1], px[k][2] * px[k][2]));
        if (slice == 0) qn[qrow * KPT + k] = x2;
        #pragma unroll
        for (int d = 0; d < 3; ++d) xn[k][d] = -2.0f * px[k][d];
        mn[k] = INFINITY;
    }

    __syncthreads();

    // min over this slice's targets of d' = |t|^2 - 2 q.t
    const int j0 = slice * TPS;
    #pragma unroll 8
    for (int j = j0; j < j0 + TPS; j += 2) {
        float4 ta = ty[j];               // 2 distinct addrs per wave (free)
        float4 tc = ty[j + 1];
        #pragma unroll
        for (int k = 0; k < KPT; ++k) {
            float da = fmaf(xn[k][0], ta.x,
                       fmaf(xn[k][1], ta.y, fmaf(xn[k][2], ta.z, ta.w)));
            float db = fmaf(xn[k][0], tc.x,
                       fmaf(xn[k][1], tc.y, fmaf(xn[k][2], tc.z, tc.w)));
            float m;
            asm("v_min3_f32 %0, %1, %2, %3"
                : "=v"(m) : "v"(mn[k]), "v"(da), "v"(db));
            mn[k] = m;                   // 3.5 VALU ops per pair
        }
    }

    // intra-wave combine of slice pairs (lanes l <-> l+32), then exchange
    #pragma unroll
    for (int k = 0; k < KPT; ++k)
        mn[k] = fminf(mn[k], __shfl_xor(mn[k], 32, 64));
    if ((slice & 1) == 0) {
        #pragma unroll
        for (int k = 0; k < KPT; ++k)
            pmin[slice >> 1][qrow * KPT + k] = mn[k];
    }
    __syncthreads();

    float val = 0.0f;
    if (tid < QPB) {                     // thread tid owns query tid
        float m = pmin[0][tid];
        #pragma unroll
        for (int s = 1; s < S / 2; ++s) m = fminf(m, pmin[s][tid]);
        val = fmaxf(qn[tid] + m, 0.0f);  // clamp after full min
    }

    // fixed-order block sum (other waves contribute 0)
    for (int off = 32; off; off >>= 1) val += __shfl_down(val, off, 64);
    if ((tid & 63) == 0) rsum[tid >> 6] = val;
    __syncthreads();
    if (tid == 0) {
        float s = 0.0f;
        #pragma unroll
        for (int i = 0; i < T / 64; ++i) s += rsum[i];
        ps[bid] = s * w[b] * (1.0f / ((float)NP * (float)BATCH));
    }
}

__global__ __launch_bounds__(64) void chamfer_final(
    const float* __restrict__ ps, float* __restrict__ out)
{
    const int l = threadIdx.x;           // one wave
    float4 v = reinterpret_cast<const float4*>(ps)[l];
    float s = (v.x + v.y) + (v.z + v.w);
    for (int off = 32; off; off >>= 1) s += __shfl_down(s, off, 64);
    if (l == 0) out[0] = s;
}

extern "C" void kernel_launch(void* const* d_in, const int* in_sizes, int n_in,
                              void* d_out, int out_size, void* d_ws, size_t ws_size,
                              hipStream_t stream) {
    const float* x = (const float*)d_in[0];   // (8, 4096, 3)
    const float* y = (const float*)d_in[1];   // (8, 4096, 3)
    const float* w = (const float*)d_in[2];   // (8,)
    float* out = (float*)d_out;
    float* ps  = (float*)d_ws;                // 256 floats

    chamfer_main<<<256, T, 0, stream>>>(x, y, w, ps);
    chamfer_final<<<1, 64, 0, stream>>>(ps, out);
}